// Round 3
// baseline (2848.291 us; speedup 1.0000x reference)
//
#include <hip/hip_runtime.h>

typedef unsigned short u16;
typedef short v8s __attribute__((ext_vector_type(8)));   // 8 x bf16 (as raw shorts)
typedef float v4f __attribute__((ext_vector_type(4)));

#define DEV __device__ __forceinline__

constexpr int BATCH = 128;
constexpr int T = 200;
constexpr int C = 512;
constexpr int H = 16;
constexpr int BT = BATCH * T;        // 25600
constexpr int TP = 208;              // T padded to 16
constexpr int TPK = 224;             // T padded to 32
constexpr int HK = 1024;             // H*64
constexpr int HC = 8192;             // H*C
constexpr float SCALE = 0.125f;      // 1/sqrt(64)

DEV u16 f2b(float x) {               // f32 -> bf16 RNE
  union { float f; unsigned u; } v; v.f = x;
  unsigned r = v.u + 0x7fffu + ((v.u >> 16) & 1u);
  return (u16)(r >> 16);
}

// ---------------- elementwise cast f32 -> bf16 ----------------
__global__ void cast_bf16_kernel(const float* __restrict__ in, u16* __restrict__ out, long n4) {
  long i = (long)blockIdx.x * blockDim.x + threadIdx.x;
  long stride = (long)gridDim.x * blockDim.x;
  for (; i < n4; i += stride) {
    float4 v = *(const float4*)(in + i * 4);
    uint2 o;
    o.x = (unsigned)f2b(v.x) | ((unsigned)f2b(v.y) << 16);
    o.y = (unsigned)f2b(v.z) | ((unsigned)f2b(v.w) << 16);
    *(uint2*)(out + i * 4) = o;
  }
}

// ---------------- transpose + cast: in f32 (R x Cc) -> out bf16 (Cc x Rpad), zero pad ----------------
__global__ void transpose_cast_kernel(const float* __restrict__ in, u16* __restrict__ out,
                                      int R, int Cc, int Rpad, long inBatch, long outBatch) {
  __shared__ float tile[32][33];
  int b = blockIdx.z;
  int c0 = blockIdx.x * 32, r0 = blockIdx.y * 32;
  int tx = threadIdx.x, ty = threadIdx.y;
  const float* ib = in + (long)b * inBatch;
  u16* ob = out + (long)b * outBatch;
  for (int i = ty; i < 32; i += 8) {
    int r = r0 + i, c = c0 + tx;
    tile[i][tx] = (r < R && c < Cc) ? ib[(long)r * Cc + c] : 0.f;
  }
  __syncthreads();
  for (int i = ty; i < 32; i += 8) {
    int c = c0 + i, r = r0 + tx;
    if (c < Cc && r < Rpad) ob[(long)c * Rpad + r] = f2b(tile[tx][i]);
  }
}

// ---------------- cvec: init with bp, then parallel bv@Wp via atomics ----------------
__global__ void cvec_init_kernel(const float* __restrict__ bp, float* __restrict__ cvec) {
  int j = threadIdx.x + blockIdx.x * 256;
  if (j < C) cvec[j] = bp[j];
}
__global__ void cvec_kernel(const float* __restrict__ bv, const float* __restrict__ Wp,
                            float* __restrict__ cvec) {
  int j = blockIdx.x * 256 + threadIdx.x;        // 2 j-chunks
  int hc0 = blockIdx.y * 256;                    // 32 hc-chunks
  float acc = 0.f;
  for (int i = 0; i < 256; i++) {
    int hc = hc0 + i;
    acc += bv[hc] * Wp[(long)hc * C + j];
  }
  atomicAdd(&cvec[j], acc);
}

// ---------------- GEMM: D = A (MxK, bf16) * Bt(NxK, bf16)^T [+bias] ; 128x128 tile, BK=64 ----------------
template<bool OUT_BF16, bool BIAS, bool ACCUM>
__global__ __launch_bounds__(256) void gemm_nt_kernel(
    const u16* __restrict__ A, long lda, long strideA,
    const u16* __restrict__ Bt, long ldb, long strideB,
    void* __restrict__ Dp, long ldd, long strideD,
    const float* __restrict__ bias, int K, int ntN) {
  __shared__ __align__(16) u16 As[128 * 64];
  __shared__ __align__(16) u16 Bs[128 * 64];
  int bt = blockIdx.y;
  int tn = blockIdx.x % ntN, tm = blockIdx.x / ntN;
  const u16* Ab = A + (long)bt * strideA + (long)tm * 128 * lda;
  const u16* Bb = Bt + (long)bt * strideB + (long)tn * 128 * ldb;
  int tid = threadIdx.x;
  int lane = tid & 63, wave = tid >> 6;
  int r15 = lane & 15, kg = lane >> 4;
  int wm = (wave & 1) * 64, wn = (wave >> 1) * 64;
  v4f acc[4][4] = {};
  for (int kt = 0; kt < K; kt += 64) {
    uint4 va[4], vb[4];
    #pragma unroll
    for (int i = 0; i < 4; i++) {
      int c = i * 256 + tid;
      long row = c >> 3; int c8 = (c & 7) * 8;
      va[i] = *(const uint4*)(Ab + row * lda + kt + c8);
      vb[i] = *(const uint4*)(Bb + row * ldb + kt + c8);
    }
    __syncthreads();
    #pragma unroll
    for (int i = 0; i < 4; i++) {
      int c = i * 256 + tid;
      *(uint4*)(As + c * 8) = va[i];
      *(uint4*)(Bs + c * 8) = vb[i];
    }
    __syncthreads();
    #pragma unroll
    for (int ks = 0; ks < 2; ks++) {
      v8s af[4], bf_[4];
      int ko = ks * 32 + kg * 8;
      #pragma unroll
      for (int mi = 0; mi < 4; mi++) af[mi] = *(const v8s*)(As + (wm + mi * 16 + r15) * 64 + ko);
      #pragma unroll
      for (int ni = 0; ni < 4; ni++) bf_[ni] = *(const v8s*)(Bs + (wn + ni * 16 + r15) * 64 + ko);
      #pragma unroll
      for (int mi = 0; mi < 4; mi++)
        #pragma unroll
        for (int ni = 0; ni < 4; ni++)
          acc[mi][ni] = __builtin_amdgcn_mfma_f32_16x16x32_bf16(af[mi], bf_[ni], acc[mi][ni], 0, 0, 0);
    }
    __syncthreads();
  }
  #pragma unroll
  for (int mi = 0; mi < 4; mi++) {
    #pragma unroll
    for (int ni = 0; ni < 4; ni++) {
      int colg = tn * 128 + wn + ni * 16 + r15;
      float bb = BIAS ? bias[colg] : 0.f;
      #pragma unroll
      for (int r = 0; r < 4; r++) {
        long rowg = (long)tm * 128 + wm + mi * 16 + kg * 4 + r;
        long off = (long)bt * strideD + rowg * ldd + colg;
        float v = acc[mi][ni][r] + bb;
        if (OUT_BF16)      ((u16*)Dp)[off] = f2b(v);
        else if (ACCUM)    ((float*)Dp)[off] += v;
        else               ((float*)Dp)[off] = v;
      }
    }
  }
}

// ---------------- fused scores + causal softmax; writes att (f32) ----------------
__global__ __launch_bounds__(256) void attn_kernel(
    const u16* __restrict__ qb, const u16* __restrict__ kb, float* __restrict__ att) {
  __shared__ __align__(16) u16 Qs[TP * 64];
  __shared__ __align__(16) u16 Ks[TP * 64];
  int bh = blockIdx.x;
  int b = bh >> 4, h = bh & 15;
  int tid = threadIdx.x;
  const u16* qg = qb + (long)b * T * HK + h * 64;
  const u16* kg_ = kb + (long)b * T * HK + h * 64;
  for (int c = tid; c < TP * 8; c += 256) {
    long row = c >> 3; int c8 = (c & 7) * 8;
    long srow = row < T ? row : (T - 1);   // clamp: stay in-bounds for pad rows
    *(uint4*)(Qs + c * 8) = *(const uint4*)(qg + srow * HK + c8);
    *(uint4*)(Ks + c * 8) = *(const uint4*)(kg_ + srow * HK + c8);
  }
  __syncthreads();
  int lane = tid & 63, wave = tid >> 6;
  int r15 = lane & 15, kg4 = lane >> 4;
  float* attb = att + (long)bh * T * T;
  for (int tt = wave; tt < 13; tt += 4) {
    v8s aq0 = *(const v8s*)(Qs + (tt * 16 + r15) * 64 + kg4 * 8);
    v8s aq1 = *(const v8s*)(Qs + (tt * 16 + r15) * 64 + 32 + kg4 * 8);
    float sc[13][4];
    #pragma unroll
    for (int j = 0; j < 13; j++) {
      if (j <= tt) {
        v8s bk0 = *(const v8s*)(Ks + (j * 16 + r15) * 64 + kg4 * 8);
        v8s bk1 = *(const v8s*)(Ks + (j * 16 + r15) * 64 + 32 + kg4 * 8);
        v4f a_ = {};
        a_ = __builtin_amdgcn_mfma_f32_16x16x32_bf16(aq0, bk0, a_, 0, 0, 0);
        a_ = __builtin_amdgcn_mfma_f32_16x16x32_bf16(aq1, bk1, a_, 0, 0, 0);
        #pragma unroll
        for (int r = 0; r < 4; r++) {
          int t_ = tt * 16 + kg4 * 4 + r;
          int s_ = j * 16 + r15;
          sc[j][r] = (s_ <= t_) ? a_[r] * SCALE : -__builtin_inff();
        }
      } else {
        #pragma unroll
        for (int r = 0; r < 4; r++) sc[j][r] = -__builtin_inff();
      }
    }
    float sm[4];
    #pragma unroll
    for (int r = 0; r < 4; r++) {
      float m = sc[0][r];
      #pragma unroll
      for (int j = 1; j < 13; j++) m = fmaxf(m, sc[j][r]);
      #pragma unroll
      for (int off = 1; off < 16; off <<= 1) m = fmaxf(m, __shfl_xor(m, off));
      float s = 0.f;
      #pragma unroll
      for (int j = 0; j < 13; j++) { float p = __expf(sc[j][r] - m); sc[j][r] = p; s += p; }
      #pragma unroll
      for (int off = 1; off < 16; off <<= 1) s += __shfl_xor(s, off);
      sm[r] = 1.f / s;
    }
    #pragma unroll
    for (int j = 0; j < 13; j++) {
      int s_ = j * 16 + r15;
      if (s_ < T) {
        #pragma unroll
        for (int r = 0; r < 4; r++) {
          int t_ = tt * 16 + kg4 * 4 + r;
          if (t_ < T) attb[(long)t_ * T + s_] = sc[j][r] * sm[r];
        }
      }
    }
  }
}

// ---------------- z = att @ x  (per (b,h)); A=att f32 from d_out, B=xbT bf16; causal K-skip ----------------
__global__ __launch_bounds__(256) void z_kernel(
    const float* __restrict__ att, const u16* __restrict__ xbT,
    u16* __restrict__ zb, int h0, int nhc) {
  __shared__ __align__(16) u16 As_[64 * 32];
  __shared__ __align__(16) u16 Bs_[128 * 32];
  int tt = blockIdx.x & 3, ny = blockIdx.x >> 2;
  int b = blockIdx.y / nhc, hh = blockIdx.y % nhc;
  int h = h0 + hh;
  const float* ab = att + (long)(b * H + h) * T * T;
  const u16* xg = xbT + (long)b * C * TPK;
  int tid = threadIdx.x;
  int lane = tid & 63, wave = tid >> 6;
  int r15 = lane & 15, kg4 = lane >> 4;
  int wm = (wave & 1) * 32, wn = (wave >> 1) * 64;
  v4f acc[2][4] = {};
  int ksteps = (tt + 1) * 2; if (ksteps > 7) ksteps = 7;
  int arow = tid >> 2, ac8 = (tid & 3) * 8;
  for (int ks = 0; ks < ksteps; ks++) {
    int s0 = ks * 32;
    // A tile: att rows [tt*64, +64), cols [s0, s0+32) -> bf16
    int t_ = tt * 64 + arow;
    __align__(16) u16 tmp[8];
    #pragma unroll
    for (int e = 0; e < 8; e++) {
      int s_ = s0 + ac8 + e;
      float v = (t_ < T && s_ < T) ? ab[(long)t_ * T + s_] : 0.f;
      tmp[e] = f2b(v);
    }
    // B tile: xbT rows [ny*128, +128), cols [s0, s0+32)
    int c0 = tid, c1 = 256 + tid;
    uint4 bv0 = *(const uint4*)(xg + (long)(ny * 128 + (c0 >> 2)) * TPK + s0 + (c0 & 3) * 8);
    uint4 bv1 = *(const uint4*)(xg + (long)(ny * 128 + (c1 >> 2)) * TPK + s0 + (c1 & 3) * 8);
    __syncthreads();
    *(uint4*)(As_ + arow * 32 + ac8) = *(uint4*)tmp;
    *(uint4*)(Bs_ + c0 * 8) = bv0;
    *(uint4*)(Bs_ + c1 * 8) = bv1;
    __syncthreads();
    int ko = kg4 * 8;
    v8s a0 = *(const v8s*)(As_ + (wm + r15) * 32 + ko);
    v8s a1 = *(const v8s*)(As_ + (wm + 16 + r15) * 32 + ko);
    v8s bf_[4];
    #pragma unroll
    for (int ni = 0; ni < 4; ni++) bf_[ni] = *(const v8s*)(Bs_ + (wn + ni * 16 + r15) * 32 + ko);
    #pragma unroll
    for (int ni = 0; ni < 4; ni++) {
      acc[0][ni] = __builtin_amdgcn_mfma_f32_16x16x32_bf16(a0, bf_[ni], acc[0][ni], 0, 0, 0);
      acc[1][ni] = __builtin_amdgcn_mfma_f32_16x16x32_bf16(a1, bf_[ni], acc[1][ni], 0, 0, 0);
    }
  }
  long ldz = (long)nhc * C;
  #pragma unroll
  for (int mi = 0; mi < 2; mi++) {
    #pragma unroll
    for (int ni = 0; ni < 4; ni++) {
      int i_ = ny * 128 + wn + ni * 16 + r15;
      #pragma unroll
      for (int r = 0; r < 4; r++) {
        int t_ = tt * 64 + wm + mi * 16 + kg4 * 4 + r;
        if (t_ < T) zb[(long)(b * T + t_) * ldz + (long)hh * C + i_] = f2b(acc[mi][ni][r]);
      }
    }
  }
}

extern "C" void kernel_launch(void* const* d_in, const int* in_sizes, int n_in,
                              void* d_out, int out_size, void* d_ws, size_t ws_size,
                              hipStream_t stream) {
  const float* x  = (const float*)d_in[0];
  const float* Wq = (const float*)d_in[1];
  const float* bq = (const float*)d_in[2];
  const float* Wk = (const float*)d_in[3];
  const float* bk = (const float*)d_in[4];
  const float* Wv = (const float*)d_in[5];
  const float* bv = (const float*)d_in[6];
  const float* Wp = (const float*)d_in[7];
  const float* bp = (const float*)d_in[8];
  float* out = (float*)d_out;
  float* att = out + (long)BT * C;   // second output region

  char* w = (char*)d_ws;
  auto alloc = [&](size_t bytes) -> char* {
    char* p = w; w += (bytes + 255) & ~(size_t)255; return p;
  };
  u16* xb  = (u16*)alloc((size_t)BT * C * 2);
  u16* xbT = (u16*)alloc((size_t)BATCH * C * TPK * 2);
  u16* qb  = (u16*)alloc((size_t)BT * HK * 2);
  u16* kb  = (u16*)alloc((size_t)BT * HK * 2);
  u16* wqT = (u16*)alloc((size_t)HK * C * 2);
  u16* wkT = (u16*)alloc((size_t)HK * C * 2);
  u16* wvb = (u16*)alloc((size_t)C * HC * 2);
  u16* wpT = (u16*)alloc((size_t)C * HC * 2);
  u16* w2t = (u16*)alloc((size_t)C * HC * 2);
  float* cv = (float*)alloc(C * 4);
  size_t used = (size_t)(w - (char*)d_ws);
  size_t rem = ws_size > used ? ws_size - used : 0;
  int nhc = 16;
  while (nhc > 1 && (size_t)BT * nhc * C * 2 > rem) nhc >>= 1;
  u16* zb = (u16*)alloc((size_t)BT * nhc * C * 2);

  cast_bf16_kernel<<<2048, 256, 0, stream>>>(x, xb, (long)BT * C / 4);
  cast_bf16_kernel<<<2048, 256, 0, stream>>>(Wv, wvb, (long)C * HC / 4);
  dim3 tb(32, 8);
  transpose_cast_kernel<<<dim3(C / 32, TPK / 32, BATCH), tb, 0, stream>>>(x, xbT, T, C, TPK, (long)T * C, (long)C * TPK);
  transpose_cast_kernel<<<dim3(HK / 32, C / 32, 1), tb, 0, stream>>>(Wq, wqT, C, HK, C, 0, 0);
  transpose_cast_kernel<<<dim3(HK / 32, C / 32, 1), tb, 0, stream>>>(Wk, wkT, C, HK, C, 0, 0);
  transpose_cast_kernel<<<dim3(C / 32, HC / 32, 1), tb, 0, stream>>>(Wp, wpT, HC, C, HC, 0, 0);
  cvec_init_kernel<<<2, 256, 0, stream>>>(bp, cv);
  cvec_kernel<<<dim3(2, 32), 256, 0, stream>>>(bv, Wp, cv);
  // Q/K projections: (25600 x 512) @ (512 x 1024) + bias -> bf16
  gemm_nt_kernel<true, true, false><<<dim3(200 * 8, 1), 256, 0, stream>>>(
      xb, C, 0, wqT, C, 0, qb, HK, 0, bq, C, 8);
  gemm_nt_kernel<true, true, false><<<dim3(200 * 8, 1), 256, 0, stream>>>(
      xb, C, 0, wkT, C, 0, kb, HK, 0, bk, C, 8);
  // W2t[j, h*C+i] = sum_c Wp[h*C+c, j] * Wv[i, h*C+c]  (batched over h)
  gemm_nt_kernel<true, false, false><<<dim3(16, H), 256, 0, stream>>>(
      wpT, HC, C, wvb, HC, C, w2t, HC, C, nullptr, C, 4);
  // scores + causal softmax -> att (output 1)
  attn_kernel<<<dim3(BATCH * H), 256, 0, stream>>>(qb, kb, att);
  // z = att @ x (bf16), then out = z @ W2t^T + cvec (head-chunked if ws is small)
  int nch = H / nhc;
  for (int cc = 0; cc < nch; cc++) {
    z_kernel<<<dim3(16, BATCH * nhc), 256, 0, stream>>>(att, xbT, zb, cc * nhc, nhc);
    if (cc == 0)
      gemm_nt_kernel<false, true, false><<<dim3(200 * 4, 1), 256, 0, stream>>>(
          zb, (long)nhc * C, 0, w2t + (long)cc * nhc * C, HC, 0, out, C, 0, cv, nhc * C, 4);
    else
      gemm_nt_kernel<false, false, true><<<dim3(200 * 4, 1), 256, 0, stream>>>(
          zb, (long)nhc * C, 0, w2t + (long)cc * nhc * C, HC, 0, out, C, 0, nullptr, nhc * C, 4);
  }
}

// Round 4
// 2512.703 us; speedup vs baseline: 1.1336x; 1.1336x over previous
//
#include <hip/hip_runtime.h>

typedef unsigned short u16;
typedef short v8s __attribute__((ext_vector_type(8)));   // 8 x bf16 (as raw shorts)
typedef float v4f __attribute__((ext_vector_type(4)));

#define DEV __device__ __forceinline__

constexpr int BATCH = 128;
constexpr int T = 200;
constexpr int C = 512;
constexpr int H = 16;
constexpr int BT = BATCH * T;        // 25600
constexpr int TP = 208;              // T padded to 16
constexpr int TPK = 224;             // T padded to 32 (y2t s-stride)
constexpr int HK = 1024;             // H*64
constexpr int HC = 8192;             // H*C
constexpr float SCALE = 0.125f;      // 1/sqrt(64)

DEV u16 f2b(float x) {               // f32 -> bf16 RNE
  union { float f; unsigned u; } v; v.f = x;
  unsigned r = v.u + 0x7fffu + ((v.u >> 16) & 1u);
  return (u16)(r >> 16);
}

// ---------------- elementwise cast f32 -> bf16 ----------------
__global__ void cast_bf16_kernel(const float* __restrict__ in, u16* __restrict__ out, long n4) {
  long i = (long)blockIdx.x * blockDim.x + threadIdx.x;
  long stride = (long)gridDim.x * blockDim.x;
  for (; i < n4; i += stride) {
    float4 v = *(const float4*)(in + i * 4);
    uint2 o;
    o.x = (unsigned)f2b(v.x) | ((unsigned)f2b(v.y) << 16);
    o.y = (unsigned)f2b(v.z) | ((unsigned)f2b(v.w) << 16);
    *(uint2*)(out + i * 4) = o;
  }
}

// ---------------- transpose + cast: in f32 (R x Cc) -> out bf16 (Cc x Rpad), zero pad ----------------
__global__ void transpose_cast_kernel(const float* __restrict__ in, u16* __restrict__ out,
                                      int R, int Cc, int Rpad, long inBatch, long outBatch) {
  __shared__ float tile[32][33];
  int b = blockIdx.z;
  int c0 = blockIdx.x * 32, r0 = blockIdx.y * 32;
  int tx = threadIdx.x, ty = threadIdx.y;
  const float* ib = in + (long)b * inBatch;
  u16* ob = out + (long)b * outBatch;
  for (int i = ty; i < 32; i += 8) {
    int r = r0 + i, c = c0 + tx;
    tile[i][tx] = (r < R && c < Cc) ? ib[(long)r * Cc + c] : 0.f;
  }
  __syncthreads();
  for (int i = ty; i < 32; i += 8) {
    int c = c0 + i, r = r0 + tx;
    if (c < Cc && r < Rpad) ob[(long)c * Rpad + r] = f2b(tile[tx][i]);
  }
}

// ---------------- cvec: init with bp, then parallel bv@Wp via atomics ----------------
__global__ void cvec_init_kernel(const float* __restrict__ bp, float* __restrict__ cvec) {
  int j = threadIdx.x + blockIdx.x * 256;
  if (j < C) cvec[j] = bp[j];
}
__global__ void cvec_kernel(const float* __restrict__ bv, const float* __restrict__ Wp,
                            float* __restrict__ cvec) {
  int j = blockIdx.x * 256 + threadIdx.x;        // 2 j-chunks
  int hc0 = blockIdx.y * 256;                    // 32 hc-chunks
  float acc = 0.f;
  for (int i = 0; i < 256; i++) {
    int hc = hc0 + i;
    acc += bv[hc] * Wp[(long)hc * C + j];
  }
  atomicAdd(&cvec[j], acc);
}

// ---------------- GEMM: D = A (MxK, bf16) * Bt(NxK, bf16)^T [+bias] ; 128x128 tile, BK=64 ----------------
// Y2T mode: D element (m=rowg, n=colg) is written as bf16 to
//   Dp[((colg/T)*HC + rowg)*TPK + (colg%T)]  -- i.e. y2t[b][h*512+j][s].
template<bool OUT_BF16, bool BIAS, bool ACCUM, bool Y2T>
__global__ __launch_bounds__(256) void gemm_nt_kernel(
    const u16* __restrict__ A, long lda, long strideA,
    const u16* __restrict__ Bt, long ldb, long strideB,
    void* __restrict__ Dp, long ldd, long strideD,
    const float* __restrict__ bias, int K, int ntN) {
  __shared__ __align__(16) u16 As[128 * 64];
  __shared__ __align__(16) u16 Bs[128 * 64];
  int bt = blockIdx.y;
  int tn = blockIdx.x % ntN, tm = blockIdx.x / ntN;
  const u16* Ab = A + (long)bt * strideA + (long)tm * 128 * lda;
  const u16* Bb = Bt + (long)bt * strideB + (long)tn * 128 * ldb;
  int tid = threadIdx.x;
  int lane = tid & 63, wave = tid >> 6;
  int r15 = lane & 15, kg = lane >> 4;
  int wm = (wave & 1) * 64, wn = (wave >> 1) * 64;
  v4f acc[4][4] = {};
  for (int kt = 0; kt < K; kt += 64) {
    uint4 va[4], vb[4];
    #pragma unroll
    for (int i = 0; i < 4; i++) {
      int c = i * 256 + tid;
      long row = c >> 3; int c8 = (c & 7) * 8;
      va[i] = *(const uint4*)(Ab + row * lda + kt + c8);
      vb[i] = *(const uint4*)(Bb + row * ldb + kt + c8);
    }
    __syncthreads();
    #pragma unroll
    for (int i = 0; i < 4; i++) {
      int c = i * 256 + tid;
      *(uint4*)(As + c * 8) = va[i];
      *(uint4*)(Bs + c * 8) = vb[i];
    }
    __syncthreads();
    #pragma unroll
    for (int ks = 0; ks < 2; ks++) {
      v8s af[4], bf_[4];
      int ko = ks * 32 + kg * 8;
      #pragma unroll
      for (int mi = 0; mi < 4; mi++) af[mi] = *(const v8s*)(As + (wm + mi * 16 + r15) * 64 + ko);
      #pragma unroll
      for (int ni = 0; ni < 4; ni++) bf_[ni] = *(const v8s*)(Bs + (wn + ni * 16 + r15) * 64 + ko);
      #pragma unroll
      for (int mi = 0; mi < 4; mi++)
        #pragma unroll
        for (int ni = 0; ni < 4; ni++)
          acc[mi][ni] = __builtin_amdgcn_mfma_f32_16x16x32_bf16(af[mi], bf_[ni], acc[mi][ni], 0, 0, 0);
    }
    __syncthreads();
  }
  #pragma unroll
  for (int mi = 0; mi < 4; mi++) {
    #pragma unroll
    for (int ni = 0; ni < 4; ni++) {
      int colg = tn * 128 + wn + ni * 16 + r15;
      float bb = BIAS ? bias[colg] : 0.f;
      #pragma unroll
      for (int r = 0; r < 4; r++) {
        long rowg = (long)tm * 128 + wm + mi * 16 + kg * 4 + r;
        float v = acc[mi][ni][r] + bb;
        if (Y2T) {
          int b2 = colg / T; int ss = colg - b2 * T;
          ((u16*)Dp)[((long)b2 * HC + rowg) * TPK + ss] = f2b(v);
        } else {
          long off = (long)bt * strideD + rowg * ldd + colg;
          if (OUT_BF16)      ((u16*)Dp)[off] = f2b(v);
          else if (ACCUM)    ((float*)Dp)[off] += v;
          else               ((float*)Dp)[off] = v;
        }
      }
    }
  }
}

// ---------------- fused scores + causal softmax; writes att (f32) ----------------
__global__ __launch_bounds__(256) void attn_kernel(
    const u16* __restrict__ qb, const u16* __restrict__ kb, float* __restrict__ att) {
  __shared__ __align__(16) u16 Qs[TP * 64];
  __shared__ __align__(16) u16 Ks[TP * 64];
  int bh = blockIdx.x;
  int b = bh >> 4, h = bh & 15;
  int tid = threadIdx.x;
  const u16* qg = qb + (long)b * T * HK + h * 64;
  const u16* kg_ = kb + (long)b * T * HK + h * 64;
  for (int c = tid; c < TP * 8; c += 256) {
    long row = c >> 3; int c8 = (c & 7) * 8;
    long srow = row < T ? row : (T - 1);   // clamp: stay in-bounds for pad rows
    *(uint4*)(Qs + c * 8) = *(const uint4*)(qg + srow * HK + c8);
    *(uint4*)(Ks + c * 8) = *(const uint4*)(kg_ + srow * HK + c8);
  }
  __syncthreads();
  int lane = tid & 63, wave = tid >> 6;
  int r15 = lane & 15, kg4 = lane >> 4;
  float* attb = att + (long)bh * T * T;
  for (int tt = wave; tt < 13; tt += 4) {
    v8s aq0 = *(const v8s*)(Qs + (tt * 16 + r15) * 64 + kg4 * 8);
    v8s aq1 = *(const v8s*)(Qs + (tt * 16 + r15) * 64 + 32 + kg4 * 8);
    float sc[13][4];
    #pragma unroll
    for (int j = 0; j < 13; j++) {
      if (j <= tt) {
        v8s bk0 = *(const v8s*)(Ks + (j * 16 + r15) * 64 + kg4 * 8);
        v8s bk1 = *(const v8s*)(Ks + (j * 16 + r15) * 64 + 32 + kg4 * 8);
        v4f a_ = {};
        a_ = __builtin_amdgcn_mfma_f32_16x16x32_bf16(aq0, bk0, a_, 0, 0, 0);
        a_ = __builtin_amdgcn_mfma_f32_16x16x32_bf16(aq1, bk1, a_, 0, 0, 0);
        #pragma unroll
        for (int r = 0; r < 4; r++) {
          int t_ = tt * 16 + kg4 * 4 + r;
          int s_ = j * 16 + r15;
          sc[j][r] = (s_ <= t_) ? a_[r] * SCALE : -__builtin_inff();
        }
      } else {
        #pragma unroll
        for (int r = 0; r < 4; r++) sc[j][r] = -__builtin_inff();
      }
    }
    float sm[4];
    #pragma unroll
    for (int r = 0; r < 4; r++) {
      float m = sc[0][r];
      #pragma unroll
      for (int j = 1; j < 13; j++) m = fmaxf(m, sc[j][r]);
      #pragma unroll
      for (int off = 1; off < 16; off <<= 1) m = fmaxf(m, __shfl_xor(m, off));
      float s = 0.f;
      #pragma unroll
      for (int j = 0; j < 13; j++) { float p = __expf(sc[j][r] - m); sc[j][r] = p; s += p; }
      #pragma unroll
      for (int off = 1; off < 16; off <<= 1) s += __shfl_xor(s, off);
      sm[r] = 1.f / s;
    }
    #pragma unroll
    for (int j = 0; j < 13; j++) {
      int s_ = j * 16 + r15;
      if (s_ < T) {
        #pragma unroll
        for (int r = 0; r < 4; r++) {
          int t_ = tt * 16 + kg4 * 4 + r;
          if (t_ < T) attb[(long)t_ * T + s_] = sc[j][r] * sm[r];
        }
      }
    }
  }
}

// ---------------- out = sum_h att_h @ y2t_h + cvec ; per-b batched, causal chunk skip ----------------
// grid: x = mt*4 + tn (mt: 2 t-tiles of 128, tn: 4 j-tiles of 128), y = b (local chunk)
__global__ __launch_bounds__(256) void out_kernel(
    const float* __restrict__ att, const u16* __restrict__ y2t,
    const float* __restrict__ cvec, float* __restrict__ out) {
  __shared__ __align__(16) u16 As_[128 * 32];
  __shared__ __align__(16) u16 Bs_[128 * 32];
  int bx = blockIdx.x;
  int mt = bx >> 2, tn = bx & 3;
  int b = blockIdx.y;
  int t0 = mt * 128;
  const float* ab = att + (long)b * H * T * T;     // [h][t][s]
  const u16* yb = y2t + (long)b * HC * TPK;        // [h*512+j][s]
  int tid = threadIdx.x;
  int lane = tid & 63, wave = tid >> 6;
  int r15 = lane & 15, kg4 = lane >> 4;
  int wm = (wave & 1) * 64, wn = (wave >> 1) * 64;
  int arow = tid >> 1, ac = (tid & 1) * 16;        // staging: 2 threads per row, 16 elems each
  v4f acc[4][4] = {};
  int nsc = (t0 == 0) ? 4 : 7;                     // causal: s <= max t in tile
  for (int h = 0; h < H; h++) {
    const float* ah = ab + (long)h * T * T;
    const u16* yh = yb + (long)(h * C + tn * 128) * TPK;
    for (int sc = 0; sc < nsc; sc++) {
      int s0 = sc * 32;
      // A tile: att rows [t0, t0+128), cols [s0, s0+32) -> bf16 (predicated loads: no OOB)
      int t_ = t0 + arow;
      __align__(16) u16 ta[16];
      #pragma unroll
      for (int e = 0; e < 16; e++) {
        int s_ = s0 + ac + e;
        float v = 0.f;
        if (t_ < T && s_ < T) v = ah[(long)t_ * T + s_];
        ta[e] = f2b(v);
      }
      // B tile: y2t rows (j) [tn*128, +128), cols [s0, s0+32)  (k-contiguous, no transpose)
      uint4 bv0 = *(const uint4*)(yh + (long)arow * TPK + s0 + ac);
      uint4 bv1 = *(const uint4*)(yh + (long)arow * TPK + s0 + ac + 8);
      __syncthreads();
      *(uint4*)(As_ + arow * 32 + ac) = *(uint4*)ta;
      *(uint4*)(As_ + arow * 32 + ac + 8) = *(uint4*)(ta + 8);
      *(uint4*)(Bs_ + arow * 32 + ac) = bv0;
      *(uint4*)(Bs_ + arow * 32 + ac + 8) = bv1;
      __syncthreads();
      int ko = kg4 * 8;
      v8s af[4], bf_[4];
      #pragma unroll
      for (int mi = 0; mi < 4; mi++) af[mi] = *(const v8s*)(As_ + (wm + mi * 16 + r15) * 32 + ko);
      #pragma unroll
      for (int ni = 0; ni < 4; ni++) bf_[ni] = *(const v8s*)(Bs_ + (wn + ni * 16 + r15) * 32 + ko);
      #pragma unroll
      for (int mi = 0; mi < 4; mi++)
        #pragma unroll
        for (int ni = 0; ni < 4; ni++)
          acc[mi][ni] = __builtin_amdgcn_mfma_f32_16x16x32_bf16(af[mi], bf_[ni], acc[mi][ni], 0, 0, 0);
      __syncthreads();
    }
  }
  #pragma unroll
  for (int mi = 0; mi < 4; mi++) {
    #pragma unroll
    for (int ni = 0; ni < 4; ni++) {
      int colg = tn * 128 + wn + ni * 16 + r15;
      float bb = cvec[colg];
      #pragma unroll
      for (int r = 0; r < 4; r++) {
        int t_ = t0 + wm + mi * 16 + kg4 * 4 + r;
        if (t_ < T) out[((long)b * T + t_) * C + colg] = acc[mi][ni][r] + bb;
      }
    }
  }
}

extern "C" void kernel_launch(void* const* d_in, const int* in_sizes, int n_in,
                              void* d_out, int out_size, void* d_ws, size_t ws_size,
                              hipStream_t stream) {
  const float* x  = (const float*)d_in[0];
  const float* Wq = (const float*)d_in[1];
  const float* bq = (const float*)d_in[2];
  const float* Wk = (const float*)d_in[3];
  const float* bk = (const float*)d_in[4];
  const float* Wv = (const float*)d_in[5];
  const float* bv = (const float*)d_in[6];
  const float* Wp = (const float*)d_in[7];
  const float* bp = (const float*)d_in[8];
  float* out = (float*)d_out;
  float* att = out + (long)BT * C;   // second output region

  char* w = (char*)d_ws;
  auto alloc = [&](size_t bytes) -> char* {
    char* p = w; w += (bytes + 255) & ~(size_t)255; return p;
  };
  u16* xb  = (u16*)alloc((size_t)BT * C * 2);      // 26 MB
  u16* qb  = (u16*)alloc((size_t)BT * HK * 2);     // 52 MB
  u16* kb  = (u16*)alloc((size_t)BT * HK * 2);     // 52 MB
  u16* wqT = (u16*)alloc((size_t)HK * C * 2);      // 2 MB
  u16* wkT = (u16*)alloc((size_t)HK * C * 2);      // 2 MB
  u16* w2n = (u16*)alloc((size_t)HC * C * 2);      // 16.8 MB  [h*512+j][i]
  float* cv = (float*)alloc(C * 4);
  char* scratch0 = w;                              // y2t aliases wvb/wpT (dead after W2-GEMM)
  u16* wvb = (u16*)alloc((size_t)C * HC * 2);      // 16.8 MB
  u16* wpT = (u16*)alloc((size_t)HC * C * 2);      // 16.8 MB
  u16* y2t = (u16*)scratch0;
  size_t rem = ws_size > (size_t)(scratch0 - (char*)d_ws)
             ? ws_size - (size_t)(scratch0 - (char*)d_ws) : 0;
  int nbc = 128;                                   // batch chunk for y2t (multiple of 16)
  while (nbc > 16 && (size_t)nbc * HC * TPK * 2 > rem) nbc >>= 1;

  cast_bf16_kernel<<<2048, 256, 0, stream>>>(x, xb, (long)BT * C / 4);
  cast_bf16_kernel<<<2048, 256, 0, stream>>>(Wv, wvb, (long)C * HC / 4);
  dim3 tb(32, 8);
  transpose_cast_kernel<<<dim3(HK / 32, C / 32, 1), tb, 0, stream>>>(Wq, wqT, C, HK, C, 0, 0);
  transpose_cast_kernel<<<dim3(HK / 32, C / 32, 1), tb, 0, stream>>>(Wk, wkT, C, HK, C, 0, 0);
  transpose_cast_kernel<<<dim3(C / 32, HC / 32, 1), tb, 0, stream>>>(Wp, wpT, HC, C, HC, 0, 0);
  cvec_init_kernel<<<2, 256, 0, stream>>>(bp, cv);
  cvec_kernel<<<dim3(2, 32), 256, 0, stream>>>(bv, Wp, cv);
  // Q/K projections: (25600 x 512) @ (512 x 1024) + bias -> bf16
  gemm_nt_kernel<true, true, false, false><<<dim3(200 * 8, 1), 256, 0, stream>>>(
      xb, C, 0, wqT, C, 0, qb, HK, 0, bq, C, 8);
  gemm_nt_kernel<true, true, false, false><<<dim3(200 * 8, 1), 256, 0, stream>>>(
      xb, C, 0, wkT, C, 0, kb, HK, 0, bk, C, 8);
  // w2n[h*512+j][i] = sum_c Wp[h*C+c, j] * Wv[i, h*C+c]  (batched over h)
  gemm_nt_kernel<true, false, false, false><<<dim3(16, H), 256, 0, stream>>>(
      wpT, HC, C, wvb, HC, C, w2n, C, (long)C * C, nullptr, C, 4);
  // scores + causal softmax -> att (output 1)
  attn_kernel<<<dim3(BATCH * H), 256, 0, stream>>>(qb, kb, att);
  // y2t[b][h*512+j][s] = sum_i x[b,s,i] * W2[h,i,j]  (M=8192, N=nbc*200, K=512; L3-resident inputs)
  // then out = sum_h att_h @ y2t_h + cvec
  for (int b0 = 0; b0 < BATCH; b0 += nbc) {
    int ntn = nbc * T / 128;   // 200 / 100 / 50 / 25
    gemm_nt_kernel<false, false, false, true><<<dim3(64 * ntn, 1), 256, 0, stream>>>(
        w2n, C, 0, xb + (long)b0 * T * C, C, 0, y2t, 0, 0, nullptr, C, ntn);
    out_kernel<<<dim3(8, nbc), 256, 0, stream>>>(
        att + (long)b0 * H * T * T, y2t, cv, out + (long)b0 * T * C);
  }
}

// Round 5
// 2472.437 us; speedup vs baseline: 1.1520x; 1.0163x over previous
//
#include <hip/hip_runtime.h>

typedef unsigned short u16;
typedef short v8s __attribute__((ext_vector_type(8)));   // 8 x bf16 (as raw shorts)
typedef float v4f __attribute__((ext_vector_type(4)));

#define DEV __device__ __forceinline__

constexpr int BATCH = 128;
constexpr int T = 200;
constexpr int C = 512;
constexpr int H = 16;
constexpr int BT = BATCH * T;        // 25600
constexpr int TP = 208;              // T padded to 16
constexpr int TPK = 224;             // T padded to 32 (y2t s-stride)
constexpr int HK = 1024;             // H*64
constexpr int HC = 8192;             // H*C
constexpr float SCALE = 0.125f;      // 1/sqrt(64)

DEV u16 f2b(float x) {               // f32 -> bf16 RNE
  union { float f; unsigned u; } v; v.f = x;
  unsigned r = v.u + 0x7fffu + ((v.u >> 16) & 1u);
  return (u16)(r >> 16);
}

// ---------------- elementwise cast f32 -> bf16 ----------------
__global__ void cast_bf16_kernel(const float* __restrict__ in, u16* __restrict__ out, long n4) {
  long i = (long)blockIdx.x * blockDim.x + threadIdx.x;
  long stride = (long)gridDim.x * blockDim.x;
  for (; i < n4; i += stride) {
    float4 v = *(const float4*)(in + i * 4);
    uint2 o;
    o.x = (unsigned)f2b(v.x) | ((unsigned)f2b(v.y) << 16);
    o.y = (unsigned)f2b(v.z) | ((unsigned)f2b(v.w) << 16);
    *(uint2*)(out + i * 4) = o;
  }
}

// ---------------- transpose + cast: in f32 (R x Cc) -> out bf16 (Cc x Rpad), zero pad ----------------
__global__ void transpose_cast_kernel(const float* __restrict__ in, u16* __restrict__ out,
                                      int R, int Cc, int Rpad, long inBatch, long outBatch) {
  __shared__ float tile[32][33];
  int b = blockIdx.z;
  int c0 = blockIdx.x * 32, r0 = blockIdx.y * 32;
  int tx = threadIdx.x, ty = threadIdx.y;
  const float* ib = in + (long)b * inBatch;
  u16* ob = out + (long)b * outBatch;
  for (int i = ty; i < 32; i += 8) {
    int r = r0 + i, c = c0 + tx;
    tile[i][tx] = (r < R && c < Cc) ? ib[(long)r * Cc + c] : 0.f;
  }
  __syncthreads();
  for (int i = ty; i < 32; i += 8) {
    int c = c0 + i, r = r0 + tx;
    if (c < Cc && r < Rpad) ob[(long)c * Rpad + r] = f2b(tile[tx][i]);
  }
}

// ---------------- cvec: init with bp, then parallel bv@Wp via atomics ----------------
__global__ void cvec_init_kernel(const float* __restrict__ bp, float* __restrict__ cvec) {
  int j = threadIdx.x + blockIdx.x * 256;
  if (j < C) cvec[j] = bp[j];
}
__global__ void cvec_kernel(const float* __restrict__ bv, const float* __restrict__ Wp,
                            float* __restrict__ cvec) {
  int j = blockIdx.x * 256 + threadIdx.x;        // 2 j-chunks
  int hc0 = blockIdx.y * 256;                    // 32 hc-chunks
  float acc = 0.f;
  for (int i = 0; i < 256; i++) {
    int hc = hc0 + i;
    acc += bv[hc] * Wp[(long)hc * C + j];
  }
  atomicAdd(&cvec[j], acc);
}

// LDS tile addressing with XOR swizzle: 128 rows x 8 chunks of 16B; chunk ^= row&7
DEV int lsw(int row, int chunk) { return row * 64 + ((chunk ^ (row & 7)) << 3); }

// ---------------- GEMM: D = A (MxK, bf16) * Bt(NxK, bf16)^T [+bias] ; 128x128 tile, BK=64 ----------------
// Y2T mode: D element (m=rowg, n=colg) is written as bf16 to y2t[colg/T][rowg][colg%T]
// via an LDS-staged transpose epilogue (contiguous 256B row writes, dword granularity).
template<bool OUT_BF16, bool BIAS, bool ACCUM, bool Y2T>
__global__ __launch_bounds__(256) void gemm_nt_kernel(
    const u16* __restrict__ A, long lda, long strideA,
    const u16* __restrict__ Bt, long ldb, long strideB,
    void* __restrict__ Dp, long ldd, long strideD,
    const float* __restrict__ bias, int K, int ntN) {
  __shared__ __align__(16) u16 As[128 * 64];
  __shared__ __align__(16) u16 Bs[128 * 64];
  int bt = blockIdx.y;
  // bijective XCD-chunked swizzle (all launch grids have gridDim.x % 8 == 0)
  int nwg = gridDim.x;
  int orig = blockIdx.x;
  int bxs = (orig & 7) * (nwg >> 3) + (orig >> 3);
  int tn = bxs % ntN, tm = bxs / ntN;
  const u16* Ab = A + (long)bt * strideA + (long)tm * 128 * lda;
  const u16* Bb = Bt + (long)bt * strideB + (long)tn * 128 * ldb;
  int tid = threadIdx.x;
  int lane = tid & 63, wave = tid >> 6;
  int r15 = lane & 15, kg = lane >> 4;
  int wm = (wave & 1) * 64, wn = (wave >> 1) * 64;
  v4f acc[4][4] = {};
  for (int kt = 0; kt < K; kt += 64) {
    uint4 va[4], vb[4];
    #pragma unroll
    for (int i = 0; i < 4; i++) {
      int c = i * 256 + tid;
      long row = c >> 3; int c8 = (c & 7) * 8;
      va[i] = *(const uint4*)(Ab + row * lda + kt + c8);
      vb[i] = *(const uint4*)(Bb + row * ldb + kt + c8);
    }
    __syncthreads();
    #pragma unroll
    for (int i = 0; i < 4; i++) {
      int c = i * 256 + tid;
      int row = c >> 3, chunk = c & 7;
      *(uint4*)(As + lsw(row, chunk)) = va[i];
      *(uint4*)(Bs + lsw(row, chunk)) = vb[i];
    }
    __syncthreads();
    #pragma unroll
    for (int ks = 0; ks < 2; ks++) {
      v8s af[4], bf_[4];
      int chunk = ks * 4 + kg;
      #pragma unroll
      for (int mi = 0; mi < 4; mi++) af[mi] = *(const v8s*)(As + lsw(wm + mi * 16 + r15, chunk));
      #pragma unroll
      for (int ni = 0; ni < 4; ni++) bf_[ni] = *(const v8s*)(Bs + lsw(wn + ni * 16 + r15, chunk));
      #pragma unroll
      for (int mi = 0; mi < 4; mi++)
        #pragma unroll
        for (int ni = 0; ni < 4; ni++)
          acc[mi][ni] = __builtin_amdgcn_mfma_f32_16x16x32_bf16(af[mi], bf_[ni], acc[mi][ni], 0, 0, 0);
    }
    __syncthreads();
  }
  if constexpr (Y2T) {
    // Stage the 128x128 bf16 C-tile into LDS (reuse As/Bs: rows 0-63 in As, 64-127 in Bs)
    #pragma unroll
    for (int mi = 0; mi < 4; mi++) {
      #pragma unroll
      for (int ni = 0; ni < 4; ni++) {
        int col = wn + ni * 16 + r15;
        #pragma unroll
        for (int r = 0; r < 4; r++) {
          int row = wm + mi * 16 + kg * 4 + r;
          u16* Trow = (row < 64 ? As : Bs) + (row & 63) * 128;
          Trow[col] = f2b(acc[mi][ni][r]);
        }
      }
    }
    __syncthreads();
    // Copy out: wave w handles rows w*32..w*32+31; lane l copies dword l (2 u16) of the row.
    // colg even and T even => a dword never straddles a batch boundary.
    int n0 = tn * 128;
    for (int it = 0; it < 32; it++) {
      int row = wave * 32 + it;
      const u16* Trow = (row < 64 ? As : Bs) + (row & 63) * 128;
      unsigned d = *(const unsigned*)(Trow + lane * 2);
      int colg = n0 + lane * 2;
      int b2 = colg / T;
      int ss = colg - b2 * T;
      long rowg = (long)tm * 128 + row;
      *(unsigned*)((u16*)Dp + ((long)b2 * HC + rowg) * TPK + ss) = d;
    }
  } else {
    #pragma unroll
    for (int mi = 0; mi < 4; mi++) {
      #pragma unroll
      for (int ni = 0; ni < 4; ni++) {
        int colg = tn * 128 + wn + ni * 16 + r15;
        float bb = BIAS ? bias[colg] : 0.f;
        #pragma unroll
        for (int r = 0; r < 4; r++) {
          long rowg = (long)tm * 128 + wm + mi * 16 + kg * 4 + r;
          long off = (long)bt * strideD + rowg * ldd + colg;
          float v = acc[mi][ni][r] + bb;
          if (OUT_BF16)      ((u16*)Dp)[off] = f2b(v);
          else if (ACCUM)    ((float*)Dp)[off] += v;
          else               ((float*)Dp)[off] = v;
        }
      }
    }
  }
}

// ---------------- fused scores + causal softmax; writes att (f32) ----------------
__global__ __launch_bounds__(256) void attn_kernel(
    const u16* __restrict__ qb, const u16* __restrict__ kb, float* __restrict__ att) {
  __shared__ __align__(16) u16 Qs[TP * 64];
  __shared__ __align__(16) u16 Ks[TP * 64];
  int bh = blockIdx.x;
  int b = bh >> 4, h = bh & 15;
  int tid = threadIdx.x;
  const u16* qg = qb + (long)b * T * HK + h * 64;
  const u16* kg_ = kb + (long)b * T * HK + h * 64;
  for (int c = tid; c < TP * 8; c += 256) {
    long row = c >> 3; int c8 = (c & 7) * 8;
    long srow = row < T ? row : (T - 1);   // clamp: stay in-bounds for pad rows
    *(uint4*)(Qs + c * 8) = *(const uint4*)(qg + srow * HK + c8);
    *(uint4*)(Ks + c * 8) = *(const uint4*)(kg_ + srow * HK + c8);
  }
  __syncthreads();
  int lane = tid & 63, wave = tid >> 6;
  int r15 = lane & 15, kg4 = lane >> 4;
  float* attb = att + (long)bh * T * T;
  for (int tt = wave; tt < 13; tt += 4) {
    v8s aq0 = *(const v8s*)(Qs + (tt * 16 + r15) * 64 + kg4 * 8);
    v8s aq1 = *(const v8s*)(Qs + (tt * 16 + r15) * 64 + 32 + kg4 * 8);
    float sc[13][4];
    #pragma unroll
    for (int j = 0; j < 13; j++) {
      if (j <= tt) {
        v8s bk0 = *(const v8s*)(Ks + (j * 16 + r15) * 64 + kg4 * 8);
        v8s bk1 = *(const v8s*)(Ks + (j * 16 + r15) * 64 + 32 + kg4 * 8);
        v4f a_ = {};
        a_ = __builtin_amdgcn_mfma_f32_16x16x32_bf16(aq0, bk0, a_, 0, 0, 0);
        a_ = __builtin_amdgcn_mfma_f32_16x16x32_bf16(aq1, bk1, a_, 0, 0, 0);
        #pragma unroll
        for (int r = 0; r < 4; r++) {
          int t_ = tt * 16 + kg4 * 4 + r;
          int s_ = j * 16 + r15;
          sc[j][r] = (s_ <= t_) ? a_[r] * SCALE : -__builtin_inff();
        }
      } else {
        #pragma unroll
        for (int r = 0; r < 4; r++) sc[j][r] = -__builtin_inff();
      }
    }
    float sm[4];
    #pragma unroll
    for (int r = 0; r < 4; r++) {
      float m = sc[0][r];
      #pragma unroll
      for (int j = 1; j < 13; j++) m = fmaxf(m, sc[j][r]);
      #pragma unroll
      for (int off = 1; off < 16; off <<= 1) m = fmaxf(m, __shfl_xor(m, off));
      float s = 0.f;
      #pragma unroll
      for (int j = 0; j < 13; j++) { float p = __expf(sc[j][r] - m); sc[j][r] = p; s += p; }
      #pragma unroll
      for (int off = 1; off < 16; off <<= 1) s += __shfl_xor(s, off);
      sm[r] = 1.f / s;
    }
    #pragma unroll
    for (int j = 0; j < 13; j++) {
      int s_ = j * 16 + r15;
      if (s_ < T) {
        #pragma unroll
        for (int r = 0; r < 4; r++) {
          int t_ = tt * 16 + kg4 * 4 + r;
          if (t_ < T) attb[(long)t_ * T + s_] = sc[j][r] * sm[r];
        }
      }
    }
  }
}

// ---------------- out = sum_h att_h @ y2t_h + cvec ; per-b batched, causal chunk skip ----------------
// grid: 8*nbc blocks, custom decode so the 4 tn-blocks sharing one att tile sit 8 apart
// in blockIdx.x (same XCD slot under round-robin dispatch) for L2 reuse of att.
__global__ __launch_bounds__(256) void out_kernel(
    const float* __restrict__ att, const u16* __restrict__ y2t,
    const float* __restrict__ cvec, float* __restrict__ out) {
  __shared__ __align__(16) u16 As_[128 * 32];
  __shared__ __align__(16) u16 Bs_[128 * 32];
  int g = blockIdx.x;
  int rr = g & 7;
  int tq = g >> 3;
  int tn = tq & 3;
  int idx = (tq >> 2) * 8 + rr;
  int b = idx >> 1;
  int mt = idx & 1;
  int t0 = mt * 128;
  const float* ab = att + (long)b * H * T * T;     // [h][t][s]
  const u16* yb = y2t + (long)b * HC * TPK;        // [h*512+j][s]
  int tid = threadIdx.x;
  int lane = tid & 63, wave = tid >> 6;
  int r15 = lane & 15, kg4 = lane >> 4;
  int wm = (wave & 1) * 64, wn = (wave >> 1) * 64;
  int arow = tid >> 1, ac = (tid & 1) * 16;        // staging: 2 threads per row, 16 elems each
  v4f acc[4][4] = {};
  int nsc = (t0 == 0) ? 4 : 7;                     // causal: s <= max t in tile
  for (int h = 0; h < H; h++) {
    const float* ah = ab + (long)h * T * T;
    const u16* yh = yb + (long)(h * C + tn * 128) * TPK;
    for (int sc = 0; sc < nsc; sc++) {
      int s0 = sc * 32;
      // A tile: att rows [t0, t0+128), cols [s0, s0+32) -> bf16 (predicated loads: no OOB)
      int t_ = t0 + arow;
      __align__(16) u16 ta[16];
      #pragma unroll
      for (int e = 0; e < 16; e++) {
        int s_ = s0 + ac + e;
        float v = 0.f;
        if (t_ < T && s_ < T) v = ah[(long)t_ * T + s_];
        ta[e] = f2b(v);
      }
      // B tile: y2t rows (j) [tn*128, +128), cols [s0, s0+32)  (k-contiguous, no transpose)
      uint4 bv0 = *(const uint4*)(yh + (long)arow * TPK + s0 + ac);
      uint4 bv1 = *(const uint4*)(yh + (long)arow * TPK + s0 + ac + 8);
      __syncthreads();
      *(uint4*)(As_ + arow * 32 + ac) = *(uint4*)ta;
      *(uint4*)(As_ + arow * 32 + ac + 8) = *(uint4*)(ta + 8);
      *(uint4*)(Bs_ + arow * 32 + ac) = bv0;
      *(uint4*)(Bs_ + arow * 32 + ac + 8) = bv1;
      __syncthreads();
      int ko = kg4 * 8;
      v8s af[4], bf_[4];
      #pragma unroll
      for (int mi = 0; mi < 4; mi++) af[mi] = *(const v8s*)(As_ + (wm + mi * 16 + r15) * 32 + ko);
      #pragma unroll
      for (int ni = 0; ni < 4; ni++) bf_[ni] = *(const v8s*)(Bs_ + (wn + ni * 16 + r15) * 32 + ko);
      #pragma unroll
      for (int mi = 0; mi < 4; mi++)
        #pragma unroll
        for (int ni = 0; ni < 4; ni++)
          acc[mi][ni] = __builtin_amdgcn_mfma_f32_16x16x32_bf16(af[mi], bf_[ni], acc[mi][ni], 0, 0, 0);
      __syncthreads();
    }
  }
  #pragma unroll
  for (int mi = 0; mi < 4; mi++) {
    #pragma unroll
    for (int ni = 0; ni < 4; ni++) {
      int colg = tn * 128 + wn + ni * 16 + r15;
      float bb = cvec[colg];
      #pragma unroll
      for (int r = 0; r < 4; r++) {
        int t_ = t0 + wm + mi * 16 + kg4 * 4 + r;
        if (t_ < T) out[((long)b * T + t_) * C + colg] = acc[mi][ni][r] + bb;
      }
    }
  }
}

extern "C" void kernel_launch(void* const* d_in, const int* in_sizes, int n_in,
                              void* d_out, int out_size, void* d_ws, size_t ws_size,
                              hipStream_t stream) {
  const float* x  = (const float*)d_in[0];
  const float* Wq = (const float*)d_in[1];
  const float* bq = (const float*)d_in[2];
  const float* Wk = (const float*)d_in[3];
  const float* bk = (const float*)d_in[4];
  const float* Wv = (const float*)d_in[5];
  const float* bv = (const float*)d_in[6];
  const float* Wp = (const float*)d_in[7];
  const float* bp = (const float*)d_in[8];
  float* out = (float*)d_out;
  float* att = out + (long)BT * C;   // second output region

  char* w = (char*)d_ws;
  auto alloc = [&](size_t bytes) -> char* {
    char* p = w; w += (bytes + 255) & ~(size_t)255; return p;
  };
  u16* xb  = (u16*)alloc((size_t)BT * C * 2);      // 26 MB
  u16* qb  = (u16*)alloc((size_t)BT * HK * 2);     // 52 MB
  u16* kb  = (u16*)alloc((size_t)BT * HK * 2);     // 52 MB
  u16* wqT = (u16*)alloc((size_t)HK * C * 2);      // 2 MB
  u16* wkT = (u16*)alloc((size_t)HK * C * 2);      // 2 MB
  u16* w2n = (u16*)alloc((size_t)HC * C * 2);      // 16.8 MB  [h*512+j][i]
  float* cv = (float*)alloc(C * 4);
  char* scratch0 = w;                              // y2t aliases wvb/wpT (dead after W2-GEMM)
  u16* wvb = (u16*)alloc((size_t)C * HC * 2);      // 16.8 MB
  u16* wpT = (u16*)alloc((size_t)HC * C * 2);      // 16.8 MB
  u16* y2t = (u16*)scratch0;
  size_t rem = ws_size > (size_t)(scratch0 - (char*)d_ws)
             ? ws_size - (size_t)(scratch0 - (char*)d_ws) : 0;
  int nbc = 128;                                   // batch chunk for y2t (multiple of 16)
  while (nbc > 16 && (size_t)nbc * HC * TPK * 2 > rem) nbc >>= 1;

  cast_bf16_kernel<<<2048, 256, 0, stream>>>(x, xb, (long)BT * C / 4);
  cast_bf16_kernel<<<2048, 256, 0, stream>>>(Wv, wvb, (long)C * HC / 4);
  dim3 tb(32, 8);
  transpose_cast_kernel<<<dim3(HK / 32, C / 32, 1), tb, 0, stream>>>(Wq, wqT, C, HK, C, 0, 0);
  transpose_cast_kernel<<<dim3(HK / 32, C / 32, 1), tb, 0, stream>>>(Wk, wkT, C, HK, C, 0, 0);
  transpose_cast_kernel<<<dim3(C / 32, HC / 32, 1), tb, 0, stream>>>(Wp, wpT, HC, C, HC, 0, 0);
  cvec_init_kernel<<<2, 256, 0, stream>>>(bp, cv);
  cvec_kernel<<<dim3(2, 32), 256, 0, stream>>>(bv, Wp, cv);
  // Q/K projections: (25600 x 512) @ (512 x 1024) + bias -> bf16
  gemm_nt_kernel<true, true, false, false><<<dim3(200 * 8, 1), 256, 0, stream>>>(
      xb, C, 0, wqT, C, 0, qb, HK, 0, bq, C, 8);
  gemm_nt_kernel<true, true, false, false><<<dim3(200 * 8, 1), 256, 0, stream>>>(
      xb, C, 0, wkT, C, 0, kb, HK, 0, bk, C, 8);
  // w2n[h*512+j][i] = sum_c Wp[h*C+c, j] * Wv[i, h*C+c]  (batched over h)
  gemm_nt_kernel<true, false, false, false><<<dim3(16, H), 256, 0, stream>>>(
      wpT, HC, C, wvb, HC, C, w2n, C, (long)C * C, nullptr, C, 4);
  // scores + causal softmax -> att (output 1)
  attn_kernel<<<dim3(BATCH * H), 256, 0, stream>>>(qb, kb, att);
  // y2t[b][h*512+j][s] = sum_i x[b,s,i] * W2[h,i,j]  (M=8192, N=nbc*200, K=512)
  // then out = sum_h att_h @ y2t_h + cvec
  for (int b0 = 0; b0 < BATCH; b0 += nbc) {
    int ntn = nbc * T / 128;   // 200 / 100 / 50 / 25
    gemm_nt_kernel<false, false, false, true><<<dim3(64 * ntn, 1), 256, 0, stream>>>(
        w2n, C, 0, xb + (long)b0 * T * C, C, 0, y2t, 0, 0, nullptr, C, ntn);
    out_kernel<<<dim3(8 * nbc), 256, 0, stream>>>(
        att + (long)b0 * H * T * T, y2t, cv, out + (long)b0 * T * C);
  }
}